// Round 2
// baseline (2358.721 us; speedup 1.0000x reference)
//
#include <hip/hip_runtime.h>
#include <hip/hip_bf16.h>

// WanJointTokenAttention: B=4, C=3072, T=4096, K=24 joints, CPJ=TD=128.
// One 256-thread block per (b,t). Runtime dtype sniff (bf16 vs f32 storage),
// then identical bf16-LDS / fp32-accumulate pipeline for both modes.

typedef unsigned short u16;
typedef unsigned int   u32;

namespace {
constexpr int Kc  = 24;
constexpr int CPJ = 128;
constexpr int TD  = 128;
constexpr int Tc  = 4096;
constexpr float EPS   = 1e-5f;
constexpr float SCALE = 0.08838834764831845f;  // 128^-0.5

__device__ __forceinline__ float b2f(u16 u) {
  union { u32 i; float f; } c; c.i = ((u32)u) << 16; return c.f;
}
__device__ __forceinline__ u16 f2b(float f) {
  __hip_bfloat16 h = __float2bfloat16(f);
  u16 u; __builtin_memcpy(&u, &h, 2); return u;
}

template <bool F32>
__device__ __forceinline__ float ld1(const void* p, int i) {
  return F32 ? ((const float*)p)[i] : b2f(((const u16*)p)[i]);
}
template <bool F32>
__device__ __forceinline__ u16 ld16(const void* p, long long i) {
  return F32 ? f2b(((const float*)p)[i]) : ((const u16*)p)[i];
}
// stage 8 consecutive elements (element index e, 8-aligned) into LDS as bf16
template <bool F32>
__device__ __forceinline__ void stage8(u16* dst, const void* src, int e) {
  if (F32) {
    const float4* s = (const float4*)src;
    float4 a = s[e >> 2];
    float4 b = s[(e >> 2) + 1];
    ushort4 lo = { f2b(a.x), f2b(a.y), f2b(a.z), f2b(a.w) };
    ushort4 hi = { f2b(b.x), f2b(b.y), f2b(b.z), f2b(b.w) };
    *reinterpret_cast<ushort4*>(dst)     = lo;
    *reinterpret_cast<ushort4*>(dst + 4) = hi;
  } else {
    *reinterpret_cast<uint4*>(dst) = ((const uint4*)src)[e >> 3];
  }
}
}  // namespace

#define FMA12()                                                              \
  do {                                                                       \
    float w0 = b2f(w.x), w1 = b2f(w.y), w2 = b2f(w.z), w3 = b2f(w.w);        \
    acc[0][0] += a0 * w0; acc[0][1] += a0 * w1;                              \
    acc[0][2] += a0 * w2; acc[0][3] += a0 * w3;                              \
    acc[1][0] += a1 * w0; acc[1][1] += a1 * w1;                              \
    acc[1][2] += a1 * w2; acc[1][3] += a1 * w3;                              \
    acc[2][0] += a2 * w0; acc[2][1] += a2 * w1;                              \
    acc[2][2] += a2 * w2; acc[2][3] += a2 * w3;                              \
  } while (0)

// C[24x128] = A[24x128] @ W[rs-major, rows 0..127, cols c0..c0+127] + bias
// Each thread: rows {rowg, rowg+8, rowg+16} x cols {col..col+3}.
template <bool F32, class LA, class SC>
__device__ void gemm128(int tid, LA loadA, const void* W, int rs, int c0,
                        const void* bias, int boff, SC storeC, u16* wls) {
  const int col  = (tid & 31) * 4;
  const int rowg = tid >> 5;
  float acc[3][4];
  #pragma unroll
  for (int r = 0; r < 3; ++r)
    #pragma unroll
    for (int i = 0; i < 4; ++i) acc[r][i] = ld1<F32>(bias, boff + col + i);
  for (int h = 0; h < 2; ++h) {
    __syncthreads();  // wls free to overwrite; prior phase stores visible
    #pragma unroll
    for (int u = 0; u < 4; ++u) {
      const int idx = tid + 256 * u;            // 0..1023
      const int rr = idx >> 4, c8 = (idx & 15) * 8;
      stage8<F32>(wls + rr * 128 + c8, W, (h * 64 + rr) * rs + c0 + c8);
    }
    __syncthreads();
    for (int cc = 0; cc < 64; ++cc) {
      const int c = h * 64 + cc;
      float a0 = loadA(rowg, c);
      float a1 = loadA(rowg + 8, c);
      float a2 = loadA(rowg + 16, c);
      ushort4 w = *reinterpret_cast<const ushort4*>(wls + cc * 128 + col);
      FMA12();
    }
  }
  __syncthreads();
  #pragma unroll
  for (int r = 0; r < 3; ++r)
    #pragma unroll
    for (int i = 0; i < 4; ++i) storeC(rowg + 8 * r, col + i, acc[r][i]);
}

template <bool F32>
__device__ void body(int tid, long long xbase,
                     const void* x, const void* Wtok, const void* btok,
                     const void* gnorm, const void* Wqkv, const void* bqkv,
                     const void* Wproj, const void* bproj, const void* Wfrom,
                     const void* bfrom, void* y,
                     u16* xt, float* tokf, u16* qb, u16* kb, u16* vb, u16* wls,
                     float (*attn)[25], float* rowstat) {
  const int col  = (tid & 31) * 4;
  const int rowg = tid >> 5;

  // ---- load x tile (channel-strided gather), keep for residual ----------
  #pragma unroll
  for (int j = 0; j < 12; ++j) {
    const int idx = tid + 256 * j;              // channel 0..3071
    xt[idx] = ld16<F32>(x, xbase + (long long)idx * Tc);
  }
  __syncthreads();

  // ---- tok = xt @ Wtok + btok ------------------------------------------
  gemm128<F32>(tid,
      [&](int r, int c) { return b2f(xt[r * CPJ + c]); },
      Wtok, TD, 0, btok, 0,
      [&](int r, int c, float v) { tokf[r * TD + c] = v; }, wls);
  __syncthreads();

  // ---- RMSNorm over last dim -------------------------------------------
  if (tid < 192) {
    const int row = tid >> 3, sub = tid & 7;
    const float* p = tokf + row * TD + sub * 16;
    float ss = 0.f;
    #pragma unroll
    for (int d = 0; d < 16; ++d) ss += p[d] * p[d];
    attn[row][sub] = ss;                         // scratch
  }
  __syncthreads();
  if (tid < Kc) {
    float ss = 0.f;
    #pragma unroll
    for (int s = 0; s < 8; ++s) ss += attn[tid][s];
    rowstat[tid] = 1.0f / sqrtf(ss * (1.0f / TD) + EPS);
  }
  __syncthreads();
  #pragma unroll
  for (int r = 0; r < 3; ++r) {
    const int row = rowg + 8 * r;
    const float sc = rowstat[row];
    float* p = tokf + row * TD + col;
    #pragma unroll
    for (int i = 0; i < 4; ++i) p[i] *= sc * ld1<F32>(gnorm, col + i);
  }
  __syncthreads();

  // ---- qkv = tok @ Wqkv + bqkv (3 column chunks of 128) ----------------
  for (int m = 0; m < 3; ++m) {
    u16* dst = (m == 0) ? qb : (m == 1) ? kb : vb;
    gemm128<F32>(tid,
        [&](int r, int c) { return tokf[r * TD + c]; },
        Wqkv, 3 * TD, m * TD, bqkv, m * TD,
        [&](int r, int c, float v) { dst[r * TD + c] = f2b(v); }, wls);
    __syncthreads();
  }

  // ---- scores = q @ k^T * SCALE, softmax rows --------------------------
  for (int idx = tid; idx < Kc * Kc; idx += 256) {
    const int i = idx / Kc, j = idx - i * Kc;
    const u16* qp = qb + i * TD;
    const u16* kp = kb + j * TD;
    float s = 0.f;
    for (int d = 0; d < TD; d += 4) {
      ushort4 qq = *reinterpret_cast<const ushort4*>(qp + d);
      ushort4 kk = *reinterpret_cast<const ushort4*>(kp + d);
      s += b2f(qq.x) * b2f(kk.x) + b2f(qq.y) * b2f(kk.y)
         + b2f(qq.z) * b2f(kk.z) + b2f(qq.w) * b2f(kk.w);
    }
    attn[i][j] = s * SCALE;
  }
  __syncthreads();
  if (tid < Kc) {
    float mx = -1e30f;
    #pragma unroll
    for (int j = 0; j < Kc; ++j) mx = fmaxf(mx, attn[tid][j]);
    float sum = 0.f;
    #pragma unroll
    for (int j = 0; j < Kc; ++j) {
      const float e = expf(attn[tid][j] - mx);
      attn[tid][j] = e; sum += e;
    }
    const float inv = 1.0f / sum;
    #pragma unroll
    for (int j = 0; j < Kc; ++j) attn[tid][j] *= inv;
  }
  __syncthreads();

  // ---- out1 = attn @ v  (into tokf) ------------------------------------
  {
    float acc[3][4];
    #pragma unroll
    for (int r = 0; r < 3; ++r)
      #pragma unroll
      for (int i = 0; i < 4; ++i) acc[r][i] = 0.f;
    for (int j = 0; j < Kc; ++j) {
      ushort4 w = *reinterpret_cast<const ushort4*>(vb + j * TD + col);
      float a0 = attn[rowg][j];
      float a1 = attn[rowg + 8][j];
      float a2 = attn[rowg + 16][j];
      FMA12();
    }
    __syncthreads();
    #pragma unroll
    for (int r = 0; r < 3; ++r)
      #pragma unroll
      for (int i = 0; i < 4; ++i)
        tokf[(rowg + 8 * r) * TD + col + i] = acc[r][i];
  }
  __syncthreads();

  // ---- out2 = out1 @ Wproj + bproj (into qb) ---------------------------
  gemm128<F32>(tid,
      [&](int r, int c) { return tokf[r * TD + c]; },
      Wproj, TD, 0, bproj, 0,
      [&](int r, int c, float v) { qb[r * TD + c] = f2b(v); }, wls);
  __syncthreads();

  // ---- out3 = out2 @ Wfrom + bfrom; y = x + out3 -----------------------
  gemm128<F32>(tid,
      [&](int r, int c) { return b2f(qb[r * TD + c]); },
      Wfrom, CPJ, 0, bfrom, 0,
      [&](int r, int c, float v) {
        const int ch = r * CPJ + c;
        const float res = b2f(xt[ch]) + v;
        if (F32) ((float*)y)[xbase + (long long)ch * Tc] = res;
        else     ((u16*)y)[xbase + (long long)ch * Tc]  = f2b(res);
      }, wls);
}

__global__ __launch_bounds__(256, 2) void wan_joint_attn_kernel(
    const void* x, const void* Wtok, const void* btok, const void* gnorm,
    const void* Wqkv, const void* bqkv, const void* Wproj, const void* bproj,
    const void* Wfrom, const void* bfrom, void* y) {
  __shared__ __align__(16) u16 xt[Kc * CPJ];     // 6 KB
  __shared__ float tokf[Kc * TD];                // 12 KB
  __shared__ __align__(16) u16 qb[Kc * TD];      // 6 KB
  __shared__ __align__(16) u16 kb[Kc * TD];      // 6 KB
  __shared__ __align__(16) u16 vb[Kc * TD];      // 6 KB
  __shared__ __align__(16) u16 wls[64 * 128];    // 16 KB weight half-tile
  __shared__ float attn[Kc][25];                 // 2.4 KB
  __shared__ float rowstat[32];
  __shared__ float red[256];                     // dtype-sniff scratch

  const int tid = threadIdx.x;
  const int t = blockIdx.x, b = blockIdx.y;
  const long long xbase = (long long)b * (Kc * CPJ) * Tc + t;

  // ---- dtype sniff: bf16 storage -> max|bf16(x[0..1023])| ~ 4;
  //      f32 storage -> low mantissa words decode to huge bf16 values.
  float m = 0.f;
  for (int i = tid; i < 1024; i += 256)
    m = fmaxf(m, fabsf(b2f(((const u16*)x)[i])));
  red[tid] = m;
  __syncthreads();
  if (tid < 32) {
    float mm = red[tid];
    #pragma unroll
    for (int s = 32; s < 256; s += 32) mm = fmaxf(mm, red[tid + s]);
    red[tid] = mm;
  }
  __syncthreads();
  if (tid == 0) {
    float mm = red[0];
    for (int s = 1; s < 32; ++s) mm = fmaxf(mm, red[s]);
    red[0] = mm;
  }
  __syncthreads();
  const bool isf32 = red[0] > 1e8f;   // block-uniform, deterministic

  if (isf32)
    body<true>(tid, xbase, x, Wtok, btok, gnorm, Wqkv, bqkv, Wproj, bproj,
               Wfrom, bfrom, y, xt, tokf, qb, kb, vb, wls, attn, rowstat);
  else
    body<false>(tid, xbase, x, Wtok, btok, gnorm, Wqkv, bqkv, Wproj, bproj,
                Wfrom, bfrom, y, xt, tokf, qb, kb, vb, wls, attn, rowstat);
}

extern "C" void kernel_launch(void* const* d_in, const int* in_sizes, int n_in,
                              void* d_out, int out_size, void* d_ws, size_t ws_size,
                              hipStream_t stream) {
  dim3 grid(Tc, 4);
  wan_joint_attn_kernel<<<grid, 256, 0, stream>>>(
      d_in[0], d_in[1], d_in[2], d_in[3], d_in[4], d_in[5], d_in[6], d_in[7],
      d_in[8], d_in[9], d_out);
}

// Round 4
// 1018.768 us; speedup vs baseline: 2.3153x; 2.3153x over previous
//
#include <hip/hip_runtime.h>
#include <hip/hip_bf16.h>

typedef unsigned short u16;
typedef unsigned int   u32;

namespace {
constexpr int Kc  = 24;
constexpr int CPJ = 128;
constexpr int TD  = 128;
constexpr int Tc  = 4096;
constexpr float EPS   = 1e-5f;
constexpr float SCALE = 0.08838834764831845f;  // 128^-0.5

constexpr int AS = 136;  // bf16 row stride for 32-row token-major tiles (272 B: 2-way banks)
constexpr int VS = 40;   // row stride for vT[128][.] and Pb[32][.] (80 B: 2-way banks)
constexpr int SS = 36;   // f32 row stride for scores

// packed-weight section offsets (bf16 elems): fragment chunks of 512 elems,
// chunk (ntile,kstep): elem[lane*8+j] = W[kstep*32+(lane>>4)*8+j][ntile*16+(lane&15)]
constexpr int OFF_TOK  = 0;
constexpr int OFF_QKV  = 16384;
constexpr int OFF_PROJ = 65536;
constexpr int OFF_FROM = 81920;
constexpr int WTOT     = 98304;

typedef __attribute__((ext_vector_type(8))) short short8;
typedef __attribute__((ext_vector_type(4))) float f32x4;

__device__ u16 g_wpack[WTOT];

__device__ __forceinline__ float b2f(u16 u) {
  union { u32 i; float f; } c; c.i = ((u32)u) << 16; return c.f;
}
__device__ __forceinline__ u16 f2b(float f) {
  __hip_bfloat16 h = __float2bfloat16(f);
  u16 u; __builtin_memcpy(&u, &h, 2); return u;
}
template <bool F32> __device__ __forceinline__ float ld1(const void* p, int i) {
  return F32 ? ((const float*)p)[i] : b2f(((const u16*)p)[i]);
}
template <bool F32> __device__ __forceinline__ u16 ld16(const void* p, long long i) {
  return F32 ? f2b(((const float*)p)[i]) : ((const u16*)p)[i];
}
__device__ __forceinline__ f32x4 mfma16(short8 a, short8 b, f32x4 c) {
  return __builtin_amdgcn_mfma_f32_16x16x32_bf16(a, b, c, 0, 0, 0);
}

// block-uniform dtype sniff: f32 storage -> low mantissa words decode huge as bf16
__device__ bool sniff_f32(const u16* x, float* red, int tid) {
  float m = 0.f;
  for (int i = tid; i < 1024; i += 256) m = fmaxf(m, fabsf(b2f(x[i])));
  red[tid] = m;
  __syncthreads();
  if (tid < 32) {
    float mm = red[tid];
    for (int s = tid + 32; s < 256; s += 32) mm = fmaxf(mm, red[s]);
    red[tid] = mm;
  }
  __syncthreads();
  if (tid == 0) {
    float mm = red[0];
    for (int s = 1; s < 32; ++s) mm = fmaxf(mm, red[s]);
    red[0] = mm;
  }
  __syncthreads();
  return red[0] > 1e8f;
}
}  // namespace

// ---------------- weight packing kernel (runs every launch) ----------------
template <bool F32>
__device__ void pack_body(const void* Wtok, const void* Wqkv, const void* Wproj,
                          const void* Wfrom, int gid) {
  const void* W; int Nw, base;
  if (gid < OFF_QKV)       { W = Wtok;  Nw = 128; base = OFF_TOK;  }
  else if (gid < OFF_PROJ) { W = Wqkv;  Nw = 384; base = OFF_QKV;  }
  else if (gid < OFF_FROM) { W = Wproj; Nw = 128; base = OFF_PROJ; }
  else                     { W = Wfrom; Nw = 128; base = OFF_FROM; }
  const int e = gid - base, chunk = e >> 9, rem = e & 511, lane = rem >> 3, j = rem & 7;
  const int ntile = chunk >> 2, kstep = chunk & 3;
  const int n = ntile * 16 + (lane & 15);
  const int k = kstep * 32 + (lane >> 4) * 8 + j;
  g_wpack[gid] = F32 ? f2b(((const float*)W)[k * Nw + n]) : ((const u16*)W)[k * Nw + n];
}

__global__ __launch_bounds__(256) void wan_pack_kernel(
    const void* x, const void* Wtok, const void* Wqkv, const void* Wproj,
    const void* Wfrom) {
  __shared__ float red[256];
  const int tid = threadIdx.x;
  const bool f32m = sniff_f32((const u16*)x, red, tid);
  const int gid = blockIdx.x * 256 + tid;
  if (gid < WTOT) {
    if (f32m) pack_body<true>(Wtok, Wqkv, Wproj, Wfrom, gid);
    else      pack_body<false>(Wtok, Wqkv, Wproj, Wfrom, gid);
  }
}

// ---------------- main kernel ----------------
struct __align__(16) Smem {
  u16 xt[32 * AS];     // 8704 B  x tile (+ residual); pad rows 24..31 zeroed
  u16 tokb[32 * AS];   //         tok -> later O (attn@v)
  u16 qb[32 * AS];     //         q -> later out2
  u16 kb[32 * AS];
  u16 vt[128 * VS];    // 10240 B v transposed [dim][token]
  u16 Pb[32 * VS];     // probs, K-padded with zeros
  float Sf[32 * SS];   // scores; overlays: sniff red[256], norm partial+rowstat
};

// C[32x128] = A @ Wpacked + bias, C stored bf16 row-major stride AS.
// wave: mtile = wid&1, ntiles wn*4..+3.
template <bool F32>
__device__ __forceinline__ void gemmA(const u16* A, const u16* wp, const void* bias,
                                      u16* C, int mtile, int wn, int l16, int quad,
                                      int lane) {
  const u16* arow = A + (mtile * 16 + l16) * AS + quad * 8;
  short8 af[4];
  #pragma unroll
  for (int ks = 0; ks < 4; ++ks) af[ks] = *(const short8*)(arow + ks * 32);
  #pragma unroll
  for (int i = 0; i < 4; ++i) {
    const int ntile = wn * 4 + i;
    const float bv = ld1<F32>(bias, ntile * 16 + l16);
    f32x4 acc = {bv, bv, bv, bv};
    #pragma unroll
    for (int ks = 0; ks < 4; ++ks) {
      short8 bf = *(const short8*)(wp + (ntile * 4 + ks) * 512 + lane * 8);
      acc = mfma16(af[ks], bf, acc);
    }
    u16* p = C + (mtile * 16 + quad * 4) * AS + ntile * 16 + l16;
    p[0] = f2b(acc[0]); p[AS] = f2b(acc[1]);
    p[2 * AS] = f2b(acc[2]); p[3 * AS] = f2b(acc[3]);
  }
}

template <bool F32>
__device__ void main_body(Smem& s, int tid, long long xbase, const void* x,
                          const void* btok, const void* gnorm, const void* bqkv,
                          const void* bproj, const void* bfrom, void* y) {
  const int lane = tid & 63, wid = tid >> 6;
  const int l16 = lane & 15, quad = lane >> 4;
  const int mtile = wid & 1, wn = wid >> 1;

  // ---- init: zero Pb (K-pad safety) + xt pad rows; load x tile ----------
  for (int i = tid; i < 32 * VS; i += 256) s.Pb[i] = 0;
  for (int i = tid; i < 8 * AS; i += 256) s.xt[24 * AS + i] = 0;
  #pragma unroll
  for (int j = 0; j < 12; ++j) {
    const int idx = tid + 256 * j;  // channel 0..3071
    s.xt[(idx >> 7) * AS + (idx & 127)] = ld16<F32>(x, xbase + (long long)idx * Tc);
  }
  __syncthreads();

  // ---- tok = xt @ Wtok + btok ------------------------------------------
  gemmA<F32>(s.xt, g_wpack + OFF_TOK, btok, s.tokb, mtile, wn, l16, quad, lane);
  __syncthreads();

  // ---- RMSNorm rows 0..23 (in-place bf16) ------------------------------
  float* partial = s.Sf;        // 192 floats
  float* rowstat = s.Sf + 192;  // 24 floats
  if (tid < 192) {
    const int row = tid >> 3, sub = tid & 7;
    const u16* p = s.tokb + row * AS + sub * 16;
    float ss = 0.f;
    #pragma unroll
    for (int d = 0; d < 16; ++d) { const float v = b2f(p[d]); ss += v * v; }
    partial[tid] = ss;
  }
  __syncthreads();
  if (tid < 24) {
    float ss = 0.f;
    #pragma unroll
    for (int u = 0; u < 8; ++u) ss += partial[tid * 8 + u];
    rowstat[tid] = rsqrtf(ss * (1.0f / TD) + EPS);
  }
  __syncthreads();
  if (tid < 192) {
    const int row = tid >> 3, sub = tid & 7;
    u16* p = s.tokb + row * AS + sub * 16;
    const float rs = rowstat[row];
    #pragma unroll
    for (int d = 0; d < 16; ++d)
      p[d] = f2b(b2f(p[d]) * rs * ld1<F32>(gnorm, sub * 16 + d));
  }
  __syncthreads();

  // ---- qkv = tok @ Wqkv + bqkv; v stored transposed --------------------
  {
    const u16* wp = g_wpack + OFF_QKV;
    const u16* arow = s.tokb + (mtile * 16 + l16) * AS + quad * 8;
    short8 af[4];
    #pragma unroll
    for (int ks = 0; ks < 4; ++ks) af[ks] = *(const short8*)(arow + ks * 32);
    for (int g = 0; g < 3; ++g) {
      #pragma unroll
      for (int i = 0; i < 4; ++i) {
        const int nn = wn + i * 2;       // 0..7 within segment
        const int ntile = g * 8 + nn;    // 0..23
        const float bv = ld1<F32>(bqkv, ntile * 16 + l16);
        f32x4 acc = {bv, bv, bv, bv};
        #pragma unroll
        for (int ks = 0; ks < 4; ++ks) {
          short8 bf = *(const short8*)(wp + (ntile * 4 + ks) * 512 + lane * 8);
          acc = mfma16(af[ks], bf, acc);
        }
        if (g == 2) {
          ushort4 v4 = {f2b(acc[0]), f2b(acc[1]), f2b(acc[2]), f2b(acc[3])};
          *reinterpret_cast<ushort4*>(s.vt + (nn * 16 + l16) * VS + mtile * 16 +
                                      quad * 4) = v4;
        } else {
          u16* dst = g ? s.kb : s.qb;
          u16* p = dst + (mtile * 16 + quad * 4) * AS + nn * 16 + l16;
          p[0] = f2b(acc[0]); p[AS] = f2b(acc[1]);
          p[2 * AS] = f2b(acc[2]); p[3 * AS] = f2b(acc[3]);
        }
      }
    }
  }
  __syncthreads();

  // ---- S = q @ k^T * SCALE (one 16x16 tile per wave) -------------------
  {
    // BUGFIX R3->R4: fragment loads MUST include the per-quad k-offset
    // (+ quad*8); R3 omitted it here (only here), corrupting attention.
    const u16* qrow = s.qb + (mtile * 16 + l16) * AS + quad * 8;
    const u16* krow = s.kb + (wn * 16 + l16) * AS + quad * 8;
    f32x4 acc = {0.f, 0.f, 0.f, 0.f};
    #pragma unroll
    for (int ks = 0; ks < 4; ++ks) {
      short8 a = *(const short8*)(qrow + ks * 32);
      short8 b = *(const short8*)(krow + ks * 32);
      acc = mfma16(a, b, acc);
    }
    float* sp = s.Sf + (mtile * 16 + quad * 4) * SS + wn * 16 + l16;
    sp[0] = acc[0] * SCALE; sp[SS] = acc[1] * SCALE;
    sp[2 * SS] = acc[2] * SCALE; sp[3 * SS] = acc[3] * SCALE;
  }
  __syncthreads();

  // ---- softmax rows 0..23 over cols 0..23 -> Pb (bf16, zero-padded) ----
  if (tid < 24) {
    const float* sr = s.Sf + tid * SS;
    float mx = -1e30f;
    #pragma unroll
    for (int j = 0; j < 24; ++j) mx = fmaxf(mx, sr[j]);
    float sum = 0.f; float e[24];
    #pragma unroll
    for (int j = 0; j < 24; ++j) { e[j] = expf(sr[j] - mx); sum += e[j]; }
    const float inv = 1.0f / sum;
    u16* pr = s.Pb + tid * VS;
    #pragma unroll
    for (int j = 0; j < 24; ++j) pr[j] = f2b(e[j] * inv);
  }
  __syncthreads();

  // ---- O = P @ v (K=32, single MFMA per tile) -> tokb ------------------
  {
    short8 ap = *(const short8*)(s.Pb + (mtile * 16 + l16) * VS + quad * 8);
    #pragma unroll
    for (int i = 0; i < 4; ++i) {
      const int nt = wn * 4 + i;
      short8 bv = *(const short8*)(s.vt + (nt * 16 + l16) * VS + quad * 8);
      f32x4 acc = {0.f, 0.f, 0.f, 0.f};
      acc = mfma16(ap, bv, acc);
      u16* p = s.tokb + (mtile * 16 + quad * 4) * AS + nt * 16 + l16;
      p[0] = f2b(acc[0]); p[AS] = f2b(acc[1]);
      p[2 * AS] = f2b(acc[2]); p[3 * AS] = f2b(acc[3]);
    }
  }
  __syncthreads();

  // ---- out2 = O @ Wproj + bproj -> qb ----------------------------------
  gemmA<F32>(s.tokb, g_wpack + OFF_PROJ, bproj, s.qb, mtile, wn, l16, quad, lane);
  __syncthreads();

  // ---- out3 = out2 @ Wfrom + bfrom; y = x + out3 -----------------------
  {
    const u16* arow = s.qb + (mtile * 16 + l16) * AS + quad * 8;
    const u16* wp = g_wpack + OFF_FROM;
    short8 af[4];
    #pragma unroll
    for (int ks = 0; ks < 4; ++ks) af[ks] = *(const short8*)(arow + ks * 32);
    #pragma unroll
    for (int i = 0; i < 4; ++i) {
      const int ntile = wn * 4 + i;
      const float bv = ld1<F32>(bfrom, ntile * 16 + l16);
      f32x4 acc = {bv, bv, bv, bv};
      #pragma unroll
      for (int ks = 0; ks < 4; ++ks) {
        short8 bf = *(const short8*)(wp + (ntile * 4 + ks) * 512 + lane * 8);
        acc = mfma16(af[ks], bf, acc);
      }
      const int row0 = mtile * 16 + quad * 4;
      if (row0 < 24) {
        #pragma unroll
        for (int r = 0; r < 4; ++r) {
          const int row = row0 + r;
          const int cc = ntile * 16 + l16;
          const long long off = xbase + (long long)(row * CPJ + cc) * Tc;
          const float res = b2f(s.xt[row * AS + cc]) + acc[r];
          if (F32) ((float*)y)[off] = res;
          else     ((u16*)y)[off] = f2b(res);
        }
      }
    }
  }
}

__global__ __launch_bounds__(256, 3) void wan_main_kernel(
    const void* x, const void* btok, const void* gnorm, const void* bqkv,
    const void* bproj, const void* bfrom, void* y) {
  __shared__ Smem s;
  const int tid = threadIdx.x;
  // XCD-aware swizzle: consecutive-t blocks on the same XCD for L2 line merge
  const int id = blockIdx.x;
  const int bt = (id & 7) * 2048 + (id >> 3);
  const int b = bt >> 12, t = bt & 4095;
  const long long xbase = (long long)b * (Kc * CPJ) * Tc + t;

  const bool f32m = sniff_f32((const u16*)x, s.Sf, tid);
  if (f32m)
    main_body<true>(s, tid, xbase, x, btok, gnorm, bqkv, bproj, bfrom, y);
  else
    main_body<false>(s, tid, xbase, x, btok, gnorm, bqkv, bproj, bfrom, y);
}

extern "C" void kernel_launch(void* const* d_in, const int* in_sizes, int n_in,
                              void* d_out, int out_size, void* d_ws, size_t ws_size,
                              hipStream_t stream) {
  wan_pack_kernel<<<384, 256, 0, stream>>>(d_in[0], d_in[1], d_in[4], d_in[6],
                                           d_in[8]);
  wan_main_kernel<<<16384, 256, 0, stream>>>(d_in[0], d_in[2], d_in[3], d_in[5],
                                             d_in[7], d_in[9], d_out);
}